// Round 3
// baseline (3500.428 us; speedup 1.0000x reference)
//
#include <hip/hip_runtime.h>
#include <hip/hip_bf16.h>
#include <math.h>

#define S 4096
#define HQ 8
#define NKVH 4
#define D 256
#define HID 2304
#define SW 2048
#define QDIM 2048
#define KVDIM 1024
#define SCALE 0.0625f
#define SOFTCAP 50.0f

typedef __hip_bfloat16 bf16;

__device__ __forceinline__ float bf2f(unsigned v) { return __uint_as_float(v << 16); }

__device__ __forceinline__ float4 ld4(const float* p) { return *(const float4*)p; }
__device__ __forceinline__ float4 ld4(const bf16* p) {
    uint2 u = *(const uint2*)p;
    return make_float4(bf2f(u.x & 0xffffu), bf2f(u.x >> 16),
                       bf2f(u.y & 0xffffu), bf2f(u.y >> 16));
}
__device__ __forceinline__ unsigned f2bf(float f) {
    unsigned u = __float_as_uint(f);
    return (u + 0x7fffu + ((u >> 16) & 1u)) >> 16;   // round-to-nearest-even
}
__device__ __forceinline__ void st4(float* p, float4 v) { *(float4*)p = v; }
__device__ __forceinline__ void st4(bf16* p, float4 v) {
    uint2 o;
    o.x = f2bf(v.x) | (f2bf(v.y) << 16);
    o.y = f2bf(v.z) | (f2bf(v.w) << 16);
    *(uint2*)p = o;
}

// C[M][N] = A[M][K] @ B[N][K]^T   (row-major, fp32 accumulate)
// 64x64 tile, BK=16, 256 threads, 4x4 micro-tile per thread.
template <typename TA, typename TB, typename TC>
__global__ __launch_bounds__(256) void sgemm_bt(const TA* __restrict__ A,
                                                const TB* __restrict__ B,
                                                TC* __restrict__ C,
                                                int M, int N, int K)
{
    __shared__ float As[16][68];   // pad 68: float4-aligned, <=2-way bank conflicts
    __shared__ float Bs[16][68];
    const int t  = threadIdx.x;
    const int tx = t & 15, ty = t >> 4;
    const int m0 = blockIdx.y * 64, n0 = blockIdx.x * 64;
    const int lm = t >> 2, lk = (t & 3) * 4;

    float c[4][4] = {};
    for (int k0 = 0; k0 < K; k0 += 16) {
        float4 av = ld4(A + (size_t)(m0 + lm) * K + k0 + lk);
        float4 bv = ld4(B + (size_t)(n0 + lm) * K + k0 + lk);
        __syncthreads();
        As[lk + 0][lm] = av.x; As[lk + 1][lm] = av.y; As[lk + 2][lm] = av.z; As[lk + 3][lm] = av.w;
        Bs[lk + 0][lm] = bv.x; Bs[lk + 1][lm] = bv.y; Bs[lk + 2][lm] = bv.z; Bs[lk + 3][lm] = bv.w;
        __syncthreads();
        #pragma unroll
        for (int k = 0; k < 16; ++k) {
            float4 a4 = *(const float4*)(&As[k][ty * 4]);
            float4 b4 = *(const float4*)(&Bs[k][tx * 4]);
            float a[4] = {a4.x, a4.y, a4.z, a4.w};
            float b[4] = {b4.x, b4.y, b4.z, b4.w};
            #pragma unroll
            for (int i = 0; i < 4; ++i)
                #pragma unroll
                for (int j = 0; j < 4; ++j)
                    c[i][j] += a[i] * b[j];
        }
    }
    #pragma unroll
    for (int i = 0; i < 4; ++i) {
        float4 v = make_float4(c[i][0], c[i][1], c[i][2], c[i][3]);
        st4(C + (size_t)(m0 + ty * 4 + i) * N + n0 + tx * 4, v);
    }
}

// In-place RoPE on Q [S][2048] and K [S][1024]; folds SCALE into Q.
__global__ __launch_bounds__(256) void rope_kernel(float* __restrict__ Q,
                                                   float* __restrict__ K,
                                                   const int* __restrict__ pos_ids)
{
    int id   = blockIdx.x * 256 + threadIdx.x;   // S * 12 * 128 threads
    int d    = id & 127;
    int rest = id >> 7;
    int hh   = rest % 12;
    int i    = rest / 12;
    float pos = (float)pos_ids[i];
    // inv_freq = 10000^(-d/128) = exp(-d * ln(1e4)/128)
    float inv = __expf((float)d * (-9.210340371976184f / 128.0f));
    float ang = pos * inv;
    float sn, cs;
    sincosf(ang, &sn, &cs);
    if (hh < HQ) {
        float* p = Q + (size_t)i * QDIM + hh * D + d;
        float x0 = p[0], x1 = p[128];
        p[0]   = (x0 * cs - x1 * sn) * SCALE;
        p[128] = (x1 * cs + x0 * sn) * SCALE;
    } else {
        float* p = K + (size_t)i * KVDIM + (hh - HQ) * D + d;
        float x0 = p[0], x1 = p[128];
        p[0]   = x0 * cs - x1 * sn;
        p[128] = x1 * cs + x0 * sn;
    }
}

// Flash attention: block = (64 q-rows, 1 head), 512 threads.
// Lane (r=t/8, g=t&7): computes scores s[r][4g..4g+3] and owns output dims {4g+32k}.
// LDS xor-swizzle (col ^= 4*(row-group)) => conflict-free float4 reads everywhere.
__global__ __launch_bounds__(512) void attn_kernel(const float* __restrict__ Q,
                                                   const float* __restrict__ Kb,
                                                   const float* __restrict__ Vb,
                                                   float* __restrict__ O)
{
    __shared__ float Qs[64 * 256];   // 64 KiB
    __shared__ float Ks[32 * 256];   // 32 KiB
    __shared__ float Vs[32 * 256];   // 32 KiB
    const int t   = threadIdx.x;
    const int h   = blockIdx.y, kvh = h >> 1;
    const int i0  = blockIdx.x * 64;

    #pragma unroll
    for (int it = 0; it < 8; ++it) {        // stage Q tile (swizzled)
        int f  = it * 512 + t;
        int rr = f >> 6;
        int c4 = (f & 63) << 2;
        float4 v = ld4(Q + (size_t)(i0 + rr) * QDIM + h * D + c4);
        *(float4*)(Qs + rr * 256 + (c4 ^ ((rr & 7) << 2))) = v;
    }

    const int r = t >> 3;
    const int g = t & 7;
    const int lanebase = (t & 63) & ~7;
    const int i = i0 + r;
    const int qsw = (r & 7) << 2;
    const float* qrow = Qs + r * 256;

    float m_r = -INFINITY, l_r = 0.0f;
    float4 acc[8];
    #pragma unroll
    for (int k = 0; k < 8; ++k) acc[k] = make_float4(0.f, 0.f, 0.f, 0.f);

    const int jt_min = (i0 >= SW) ? ((i0 - (SW - 1)) >> 5) : 0;
    const int jt_max = (i0 + 63) >> 5;

    for (int jt = jt_min; jt <= jt_max; ++jt) {
        const int j0 = jt * 32;
        __syncthreads();
        #pragma unroll
        for (int it = 0; it < 4; ++it) {    // stage K,V tiles (swizzled)
            int f  = it * 512 + t;
            int rr = f >> 6;
            int c4 = (f & 63) << 2;
            int cs = c4 ^ (((rr >> 2) & 7) << 2);
            float4 kv = ld4(Kb + (size_t)(j0 + rr) * KVDIM + kvh * D + c4);
            float4 vv = ld4(Vb + (size_t)(j0 + rr) * KVDIM + kvh * D + c4);
            *(float4*)(Ks + rr * 256 + cs) = kv;
            *(float4*)(Vs + rr * 256 + cs) = vv;
        }
        __syncthreads();

        // ---- scores: 4 dot products of length 256 from LDS
        float s0 = 0.f, s1 = 0.f, s2 = 0.f, s3 = 0.f;
        const float* k0p = Ks + (4 * g + 0) * 256;
        const float* k1p = Ks + (4 * g + 1) * 256;
        const float* k2p = Ks + (4 * g + 2) * 256;
        const float* k3p = Ks + (4 * g + 3) * 256;
        const int ksw = g << 2;
        for (int d4 = 0; d4 < 256; d4 += 4) {
            float4 q4 = *(const float4*)(qrow + (d4 ^ qsw));
            int kc = d4 ^ ksw;
            float4 k40 = *(const float4*)(k0p + kc);
            float4 k41 = *(const float4*)(k1p + kc);
            float4 k42 = *(const float4*)(k2p + kc);
            float4 k43 = *(const float4*)(k3p + kc);
            s0 += q4.x * k40.x + q4.y * k40.y + q4.z * k40.z + q4.w * k40.w;
            s1 += q4.x * k41.x + q4.y * k41.y + q4.z * k41.z + q4.w * k41.w;
            s2 += q4.x * k42.x + q4.y * k42.y + q4.z * k42.z + q4.w * k42.w;
            s3 += q4.x * k43.x + q4.y * k43.y + q4.z * k43.z + q4.w * k43.w;
        }
        float s4[4] = {s0, s1, s2, s3};
        #pragma unroll
        for (int jj = 0; jj < 4; ++jj) {    // softcap + causal/sliding-window mask
            int j = j0 + 4 * g + jj;
            float sc = SOFTCAP * tanhf(s4[jj] * (1.0f / SOFTCAP));
            s4[jj] = ((j <= i) && (i - j < SW)) ? sc : -1e9f;
        }
        // ---- online softmax (8-lane group = one q-row)
        float mx = fmaxf(fmaxf(s4[0], s4[1]), fmaxf(s4[2], s4[3]));
        mx = fmaxf(mx, __shfl_xor(mx, 1));
        mx = fmaxf(mx, __shfl_xor(mx, 2));
        mx = fmaxf(mx, __shfl_xor(mx, 4));
        float m_new = fmaxf(m_r, mx);
        float alpha = __expf(m_r - m_new);  // -inf first iter -> 0
        float p4[4];
        float ls = 0.f;
        #pragma unroll
        for (int jj = 0; jj < 4; ++jj) { p4[jj] = __expf(s4[jj] - m_new); ls += p4[jj]; }
        ls += __shfl_xor(ls, 1); ls += __shfl_xor(ls, 2); ls += __shfl_xor(ls, 4);
        l_r = l_r * alpha + ls;
        m_r = m_new;
        #pragma unroll
        for (int k = 0; k < 8; ++k) {
            acc[k].x *= alpha; acc[k].y *= alpha; acc[k].z *= alpha; acc[k].w *= alpha;
        }
        // ---- PV accumulate: broadcast p within the 8-lane row group via shfl
        #pragma unroll
        for (int jb = 0; jb < 8; ++jb) {
            #pragma unroll
            for (int jj = 0; jj < 4; ++jj) {
                float pj = __shfl(p4[jj], lanebase + jb);
                const float* vrow = Vs + (4 * jb + jj) * 256;
                const int gx = (g << 2) ^ (jb << 2);
                #pragma unroll
                for (int k = 0; k < 8; ++k) {
                    float4 v4 = *(const float4*)(vrow + gx + 32 * k);
                    acc[k].x += pj * v4.x; acc[k].y += pj * v4.y;
                    acc[k].z += pj * v4.z; acc[k].w += pj * v4.w;
                }
            }
        }
    }
    float inv_l = 1.0f / l_r;
    float* orow = O + (size_t)i * QDIM + h * D;
    #pragma unroll
    for (int k = 0; k < 8; ++k) {
        float4 v = acc[k];
        v.x *= inv_l; v.y *= inv_l; v.z *= inv_l; v.w *= inv_l;
        *(float4*)(orow + (g << 2) + 32 * k) = v;
    }
}

extern "C" void kernel_launch(void* const* d_in, const int* in_sizes, int n_in,
                              void* d_out, int out_size, void* d_ws, size_t ws_size,
                              hipStream_t stream) {
    // Inputs fp32 (confirmed: bf16 reads -> NaN in round 1).
    // Output fp32 per the harness contract ("reference's OUTPUT dtype ... else float*").
    const float* hidden = (const float*)d_in[0];
    // d_in[1] = attention_mask: recomputed analytically, not read
    const float* Wq = (const float*)d_in[2];
    const float* Wk = (const float*)d_in[3];
    const float* Wv = (const float*)d_in[4];
    const float* Wo = (const float*)d_in[5];
    const int* pos = (const int*)d_in[6];
    float* out = (float*)d_out;

    char* ws = (char*)d_ws;
    float* Q = (float*)(ws);                 // 4096*2048 fp32 = 32 MiB
    float* K = (float*)(ws + 33554432);      // 4096*1024 fp32 = 16 MiB
    float* V = (float*)(ws + 50331648);      // 16 MiB
    float* O = (float*)(ws + 67108864);      // 32 MiB   (total 96 MiB)

    // QKV projections (fp32 in, fp32 out)
    sgemm_bt<float, float, float><<<dim3(QDIM / 64, S / 64), 256, 0, stream>>>(hidden, Wq, Q, S, QDIM, HID);
    sgemm_bt<float, float, float><<<dim3(KVDIM / 64, S / 64), 256, 0, stream>>>(hidden, Wk, K, S, KVDIM, HID);
    sgemm_bt<float, float, float><<<dim3(KVDIM / 64, S / 64), 256, 0, stream>>>(hidden, Wv, V, S, KVDIM, HID);

    // RoPE (+ SCALE folded into Q)
    rope_kernel<<<(S * 12 * 128) / 256, 256, 0, stream>>>(Q, K, pos);

    // Flash attention with softcap + sliding window
    attn_kernel<<<dim3(S / 64, HQ), 512, 0, stream>>>(Q, K, V, O);

    // Output projection (fp32 in, fp32 out)
    sgemm_bt<float, float, float><<<dim3(HID / 64, S / 64), 256, 0, stream>>>(O, Wo, out, S, HID, QDIM);
}

// Round 4
// 912.513 us; speedup vs baseline: 3.8360x; 3.8360x over previous
//
#include <hip/hip_runtime.h>
#include <hip/hip_bf16.h>
#include <math.h>

#define S 4096
#define HQ 8
#define NKVH 4
#define D 256
#define HID 2304
#define SW 2048
#define QDIM 2048
#define KVDIM 1024
#define SCALE 0.0625f
#define SOFTCAP 50.0f

typedef __hip_bfloat16 bf16;
typedef __attribute__((ext_vector_type(4))) float f32x4;
typedef __attribute__((ext_vector_type(8))) short short8;   // 8 bf16 = 4 VGPRs (MFMA A/B frag)

__device__ __forceinline__ unsigned f2bf(float f) {
    unsigned u = __float_as_uint(f);
    return (u + 0x7fffu + ((u >> 16) & 1u)) >> 16;   // round-to-nearest-even
}

__device__ __forceinline__ void store_c(float* p, float v) { *p = v; }
__device__ __forceinline__ void store_c(bf16* p, float v) { *(unsigned short*)p = (unsigned short)f2bf(v); }

// ---------------------------------------------------------------------------
// C[M][N] = A[M][K] @ B[N][K]^T, fp32 in (converted to bf16), fp32 accumulate.
// 128x128 tile, BK=32, 256 threads = 4 waves (2x2 of 64x64), 4x4 MFMA tiles/wave.
// ---------------------------------------------------------------------------
template <typename TC>
__global__ __launch_bounds__(256) void mfma_gemm_bt(const float* __restrict__ A,
                                                    const float* __restrict__ B,
                                                    TC* __restrict__ C,
                                                    int M, int N, int K)
{
    __shared__ unsigned short As[128 * 40];   // 32 bf16 data + 8 pad per row
    __shared__ unsigned short Bs[128 * 40];
    const int t = threadIdx.x;
    const int m0 = blockIdx.y * 128, n0 = blockIdx.x * 128;
    const int w = t >> 6, lid = t & 63, n16 = lid & 15, quad = lid >> 4;
    const int wm = (w >> 1) * 64, wn = (w & 1) * 64;

    f32x4 acc[4][4] = {};

    for (int k0 = 0; k0 < K; k0 += 32) {
        __syncthreads();
        #pragma unroll
        for (int it = 0; it < 4; ++it) {
            int slot = it * 256 + t;
            int row  = slot >> 3;         // 0..127
            int c4   = (slot & 7) * 4;    // 0..28
            float4 av = *(const float4*)(A + (size_t)(m0 + row) * K + k0 + c4);
            float4 bv = *(const float4*)(B + (size_t)(n0 + row) * K + k0 + c4);
            uint2 ap, bp;
            ap.x = f2bf(av.x) | (f2bf(av.y) << 16); ap.y = f2bf(av.z) | (f2bf(av.w) << 16);
            bp.x = f2bf(bv.x) | (f2bf(bv.y) << 16); bp.y = f2bf(bv.z) | (f2bf(bv.w) << 16);
            *(uint2*)(As + row * 40 + c4) = ap;
            *(uint2*)(Bs + row * 40 + c4) = bp;
        }
        __syncthreads();
        short8 af[4], bfr[4];
        #pragma unroll
        for (int x = 0; x < 4; ++x) {
            af[x]  = *(const short8*)(As + (wm + x * 16 + n16) * 40 + quad * 8);
            bfr[x] = *(const short8*)(Bs + (wn + x * 16 + n16) * 40 + quad * 8);
        }
        #pragma unroll
        for (int i = 0; i < 4; ++i)
            #pragma unroll
            for (int j = 0; j < 4; ++j)
                acc[i][j] = __builtin_amdgcn_mfma_f32_16x16x32_bf16(af[i], bfr[j], acc[i][j], 0, 0, 0);
    }

    // C/D layout: col = lane&15, row = quad*4 + reg  [verified m89/m91]
    #pragma unroll
    for (int i = 0; i < 4; ++i) {
        #pragma unroll
        for (int j = 0; j < 4; ++j) {
            int rbase = m0 + wm + i * 16 + quad * 4;
            int col   = n0 + wn + j * 16 + n16;
            #pragma unroll
            for (int rg = 0; rg < 4; ++rg)
                store_c(C + (size_t)(rbase + rg) * N + col, acc[i][j][rg]);
        }
    }
}

// ---------------------------------------------------------------------------
// RoPE: read fp32 Q/K, write bf16 Qb/Kb (SCALE folded into Q).
// ---------------------------------------------------------------------------
__global__ __launch_bounds__(256) void rope_kernel(const float* __restrict__ Qf,
                                                   const float* __restrict__ Kf,
                                                   unsigned short* __restrict__ Qb,
                                                   unsigned short* __restrict__ Kb,
                                                   const int* __restrict__ pos_ids)
{
    int id   = blockIdx.x * 256 + threadIdx.x;   // S * 12 * 128 threads
    int d    = id & 127;
    int rest = id >> 7;
    int hh   = rest % 12;
    int i    = rest / 12;
    float pos = (float)pos_ids[i];
    float inv = __expf((float)d * (-9.210340371976184f / 128.0f));   // 10000^(-d/128)
    float ang = pos * inv;
    float sn, cs;
    sincosf(ang, &sn, &cs);
    if (hh < HQ) {
        const float* p = Qf + (size_t)i * QDIM + hh * D + d;
        float x0 = p[0], x1 = p[128];
        unsigned short* q = Qb + (size_t)i * QDIM + hh * D + d;
        q[0]   = (unsigned short)f2bf((x0 * cs - x1 * sn) * SCALE);
        q[128] = (unsigned short)f2bf((x1 * cs + x0 * sn) * SCALE);
    } else {
        const float* p = Kf + (size_t)i * KVDIM + (hh - HQ) * D + d;
        float x0 = p[0], x1 = p[128];
        unsigned short* k = Kb + (size_t)i * KVDIM + (hh - HQ) * D + d;
        k[0]   = (unsigned short)f2bf(x0 * cs - x1 * sn);
        k[128] = (unsigned short)f2bf(x1 * cs + x0 * sn);
    }
}

// ---------------------------------------------------------------------------
// V transpose: Vf [S][KVDIM] fp32 -> Vt [KVDIM][S] bf16.
// ---------------------------------------------------------------------------
__global__ __launch_bounds__(256) void transpose_v(const float* __restrict__ Vf,
                                                   unsigned short* __restrict__ Vt)
{
    __shared__ float tile[64][65];
    const int s0 = blockIdx.x * 64, d0 = blockIdx.y * 64;
    const int t = threadIdx.x;
    #pragma unroll
    for (int it = 0; it < 4; ++it) {
        int flat = it * 256 + t;
        int r  = flat >> 4;          // s-row 0..63
        int c4 = (flat & 15) * 4;    // d-col 0..60
        float4 v = *(const float4*)(Vf + (size_t)(s0 + r) * KVDIM + d0 + c4);
        tile[r][c4 + 0] = v.x; tile[r][c4 + 1] = v.y;
        tile[r][c4 + 2] = v.z; tile[r][c4 + 3] = v.w;
    }
    __syncthreads();
    #pragma unroll
    for (int it = 0; it < 4; ++it) {
        int flat = it * 256 + t;
        int dr  = flat >> 4;         // d-row 0..63
        int sc4 = (flat & 15) * 4;   // s-col 0..60
        uint2 o;
        o.x = f2bf(tile[sc4 + 0][dr]) | (f2bf(tile[sc4 + 1][dr]) << 16);
        o.y = f2bf(tile[sc4 + 2][dr]) | (f2bf(tile[sc4 + 3][dr]) << 16);
        *(uint2*)(Vt + (size_t)(d0 + dr) * S + s0 + sc4) = o;
    }
}

// ---------------------------------------------------------------------------
// MFMA flash attention. Block = 256 threads (4 waves) x (64 q-rows, 1 head).
// Wave w owns q rows [i0+16w, i0+16w+16). KV tiles of 64 keys.
// Q frags in registers; K, V^T staged in LDS; P LDS round-trip (C-layout ->
// A-layout). Online softmax per q-row (per-reg stats, shfl_xor over lane&15).
// ---------------------------------------------------------------------------
#define KPITCH 272   // 256 data + 16 pad (bf16)
#define VPITCH 72    // 64 data + 8 pad
#define PPITCH 72

__global__ __launch_bounds__(256) void attn_kernel(const unsigned short* __restrict__ Qb,
                                                   const unsigned short* __restrict__ Kb,
                                                   const unsigned short* __restrict__ Vt,
                                                   float* __restrict__ O)
{
    __shared__ unsigned short Ks[64 * KPITCH];    // 34816 B
    __shared__ unsigned short Vs[256 * VPITCH];   // 36864 B
    __shared__ unsigned short Ps[4 * 16 * PPITCH]; // 9216 B  (total ~79 KiB, 2 blocks/CU)
    const int t   = threadIdx.x;
    const int h   = blockIdx.y, kvh = h >> 1;
    const int i0  = blockIdx.x * 64;
    const int w = t >> 6, lid = t & 63, n16 = lid & 15, quad = lid >> 4;
    const int qbase = i0 + w * 16;
    unsigned short* Pw = Ps + w * 16 * PPITCH;

    // Q A-frags: A[m=lane&15][k=quad*8+j], k-steps of 32 over D=256
    short8 qf[8];
    #pragma unroll
    for (int ks = 0; ks < 8; ++ks)
        qf[ks] = *(const short8*)(Qb + (size_t)(qbase + n16) * QDIM + h * D + ks * 32 + quad * 8);

    float m_old[4] = {-INFINITY, -INFINITY, -INFINITY, -INFINITY};
    float l[4] = {0.f, 0.f, 0.f, 0.f};
    f32x4 Oacc[16] = {};

    const int jt_min = (i0 >= SW) ? ((i0 - (SW - 1)) >> 6) : 0;
    const int jt_max = i0 >> 6;

    for (int jt = jt_min; jt <= jt_max; ++jt) {
        const int j0 = jt * 64;
        __syncthreads();
        #pragma unroll
        for (int it = 0; it < 8; ++it) {        // stage K: [64 keys][256 d]
            int slot = it * 256 + t;
            int key = slot >> 5;
            int d8  = (slot & 31) * 8;
            uint4 kv = *(const uint4*)(Kb + (size_t)(j0 + key) * KVDIM + kvh * D + d8);
            *(uint4*)(Ks + key * KPITCH + d8) = kv;
        }
        #pragma unroll
        for (int it = 0; it < 8; ++it) {        // stage V^T: [256 d][64 keys]
            int slot = it * 256 + t;
            int dd = slot >> 3;
            int k8 = (slot & 7) * 8;
            uint4 vv = *(const uint4*)(Vt + (size_t)(kvh * D + dd) * S + j0 + k8);
            *(uint4*)(Vs + dd * VPITCH + k8) = vv;
        }
        __syncthreads();

        // ---- S = Q K^T : 4 key-tiles of 16, 8 k-steps
        f32x4 sc[4] = {};
        #pragma unroll
        for (int nt = 0; nt < 4; ++nt) {
            #pragma unroll
            for (int ks = 0; ks < 8; ++ks) {
                short8 kf = *(const short8*)(Ks + (nt * 16 + n16) * KPITCH + ks * 32 + quad * 8);
                sc[nt] = __builtin_amdgcn_mfma_f32_16x16x32_bf16(qf[ks], kf, sc[nt], 0, 0, 0);
            }
        }

        // ---- softcap + mask (C layout: key = nt*16 + n16, q = quad*4 + reg)
        float xv[4][4];
        #pragma unroll
        for (int nt = 0; nt < 4; ++nt) {
            int j = j0 + nt * 16 + n16;
            #pragma unroll
            for (int rg = 0; rg < 4; ++rg) {
                int iq = qbase + quad * 4 + rg;
                float x = sc[nt][rg];
                float e = __expf(x * (2.0f / SOFTCAP));
                x = SOFTCAP * (1.0f - 2.0f / (e + 1.0f));    // 50*tanh(x/50)
                bool ok = (j <= iq) && (iq - j < SW);
                xv[nt][rg] = ok ? x : -1e9f;
            }
        }

        // ---- online softmax per q-row
        float alpha[4];
        #pragma unroll
        for (int rg = 0; rg < 4; ++rg) {
            float mx = fmaxf(fmaxf(xv[0][rg], xv[1][rg]), fmaxf(xv[2][rg], xv[3][rg]));
            mx = fmaxf(mx, __shfl_xor(mx, 1));
            mx = fmaxf(mx, __shfl_xor(mx, 2));
            mx = fmaxf(mx, __shfl_xor(mx, 4));
            mx = fmaxf(mx, __shfl_xor(mx, 8));
            float mnew = fmaxf(m_old[rg], mx);
            alpha[rg] = __expf(m_old[rg] - mnew);   // -inf -> 0 on first tile
            m_old[rg] = mnew;
        }
        #pragma unroll
        for (int rg = 0; rg < 4; ++rg) {
            float rs = 0.f;
            #pragma unroll
            for (int nt = 0; nt < 4; ++nt) {
                float pv = __expf(xv[nt][rg] - m_old[rg]);
                Pw[(quad * 4 + rg) * PPITCH + nt * 16 + n16] = (unsigned short)f2bf(pv);
                rs += pv;
            }
            rs += __shfl_xor(rs, 1); rs += __shfl_xor(rs, 2);
            rs += __shfl_xor(rs, 4); rs += __shfl_xor(rs, 8);
            l[rg] = l[rg] * alpha[rg] + rs;
        }
        #pragma unroll
        for (int dt = 0; dt < 16; ++dt)
            #pragma unroll
            for (int rg = 0; rg < 4; ++rg)
                Oacc[dt][rg] *= alpha[rg];

        asm volatile("s_waitcnt lgkmcnt(0)" ::: "memory");   // P writes visible (wave-private)

        // ---- O += P V : A = P[q][key] (from LDS, A-layout), B = Vt[d][key]
        #pragma unroll
        for (int ks2 = 0; ks2 < 2; ++ks2) {
            short8 pf = *(const short8*)(Pw + n16 * PPITCH + ks2 * 32 + quad * 8);
            #pragma unroll
            for (int dt = 0; dt < 16; ++dt) {
                short8 vf = *(const short8*)(Vs + (dt * 16 + n16) * VPITCH + ks2 * 32 + quad * 8);
                Oacc[dt] = __builtin_amdgcn_mfma_f32_16x16x32_bf16(pf, vf, Oacc[dt], 0, 0, 0);
            }
        }
    }

    #pragma unroll
    for (int rg = 0; rg < 4; ++rg) l[rg] = 1.0f / l[rg];
    #pragma unroll
    for (int dt = 0; dt < 16; ++dt) {
        int col = h * D + dt * 16 + n16;
        #pragma unroll
        for (int rg = 0; rg < 4; ++rg) {
            int row = qbase + quad * 4 + rg;
            O[(size_t)row * QDIM + col] = Oacc[dt][rg] * l[rg];
        }
    }
}

extern "C" void kernel_launch(void* const* d_in, const int* in_sizes, int n_in,
                              void* d_out, int out_size, void* d_ws, size_t ws_size,
                              hipStream_t stream) {
    const float* hidden = (const float*)d_in[0];
    // d_in[1] = attention_mask: recomputed analytically, not read
    const float* Wq = (const float*)d_in[2];
    const float* Wk = (const float*)d_in[3];
    const float* Wv = (const float*)d_in[4];
    const float* Wo = (const float*)d_in[5];
    const int* pos = (const int*)d_in[6];
    float* out = (float*)d_out;

    char* ws = (char*)d_ws;
    float* Qf = (float*)(ws);                                 // [S][2048] fp32, 32 MiB
    float* Kf = (float*)(ws + (size_t)(32 << 20));            // [S][1024] fp32, 16 MiB
    float* Vf = (float*)(ws + (size_t)(48 << 20));            // [S][1024] fp32, 16 MiB
    unsigned short* Qb = (unsigned short*)(ws + (size_t)(64 << 20));  // bf16, 16 MiB
    unsigned short* Kb = (unsigned short*)(ws + (size_t)(80 << 20));  // bf16,  8 MiB
    unsigned short* Vt = (unsigned short*)(ws + (size_t)(88 << 20));  // bf16,  8 MiB
    float* Oa = (float*)(ws);   // aliases Qf (dead after rope; stream order safe)

    mfma_gemm_bt<float><<<dim3(QDIM / 128, S / 128), 256, 0, stream>>>(hidden, Wq, Qf, S, QDIM, HID);
    mfma_gemm_bt<float><<<dim3(KVDIM / 128, S / 128), 256, 0, stream>>>(hidden, Wk, Kf, S, KVDIM, HID);
    mfma_gemm_bt<float><<<dim3(KVDIM / 128, S / 128), 256, 0, stream>>>(hidden, Wv, Vf, S, KVDIM, HID);

    rope_kernel<<<(S * 12 * 128) / 256, 256, 0, stream>>>(Qf, Kf, Qb, Kb, pos);
    transpose_v<<<dim3(S / 64, KVDIM / 64), 256, 0, stream>>>(Vf, Vt);

    attn_kernel<<<dim3(S / 64, HQ), 256, 0, stream>>>(Qb, Kb, Vt, Oa);

    mfma_gemm_bt<float><<<dim3(HID / 128, S / 128), 256, 0, stream>>>(Oa, Wo, out, S, HID, QDIM);
}